// Round 1
// 377.207 us; speedup vs baseline: 1.1554x; 1.1554x over previous
//
#include <hip/hip_runtime.h>
#include <hip/hip_bf16.h>

#define NN 100000
#define EE 640000
#define DD 128
#define RR 8
#define K8 (NN * RR)      // 800000 (rel,src) pair keys, key = r*NN + src
#define NSB2 196          // ceil(K8/4096)
#define GBMAX 11571       // worst-case gemm blocks: (640000+8*63+100032)/64

typedef __attribute__((ext_vector_type(8))) short short8;
typedef __attribute__((ext_vector_type(4))) float floatx4;
typedef __attribute__((ext_vector_type(4))) unsigned int uint4v;

__device__ __forceinline__ unsigned short f2bf(float f) {
  unsigned int u = __float_as_uint(f);
  u += 0x7FFFu + ((u >> 16) & 1u);   // RNE
  return (unsigned short)(u >> 16);
}
__device__ __forceinline__ unsigned int pk2bf(float a, float b) {
  __hip_bfloat162 h = __float22bfloat162_rn(make_float2(a, b));
  unsigned int u;
  __builtin_memcpy(&u, &h, 4);
  return u;                          // low16 = a, high16 = b
}
__device__ __forceinline__ float bflo(unsigned int u) { return __uint_as_float(u << 16); }
__device__ __forceinline__ float bfhi(unsigned int u) { return __uint_as_float(u & 0xFFFF0000u); }

// ---------------------------------------------------------------------------
// x (fp32 [NN][128]) -> Xb (bf16 std rows as uints: uint j = cols 2j|2j+1<<16)
// ---------------------------------------------------------------------------
__global__ __launch_bounds__(256) void xb_prep(
    const float* __restrict__ x, unsigned int* __restrict__ xb)
{
  int g = blockIdx.x * 256 + threadIdx.x;
  int v = g >> 4, seg = g & 15;
  const float4* s4 = (const float4*)(x + (size_t)v * 128 + seg * 8);
  float4 a = s4[0], b = s4[1];
  uint4v o;
  o[0] = pk2bf(a.x, a.y); o[1] = pk2bf(a.z, a.w);
  o[2] = pk2bf(b.x, b.y); o[3] = pk2bf(b.z, b.w);
  *(uint4v*)(xb + (size_t)v * 64 + seg * 4) = o;
}

// ---------------------------------------------------------------------------
// Both layers' weights: wt[set][r][n][k] = bf16(W[k][n]); r=8 is root.
// ---------------------------------------------------------------------------
__global__ __launch_bounds__(256) void w_prep_all(
    const float* __restrict__ rel1, const float* __restrict__ root1,
    const float* __restrict__ rel2, const float* __restrict__ root2,
    unsigned short* __restrict__ wt)
{
  int id = blockIdx.x * 256 + threadIdx.x;       // [0, 2*9*16384)
  int set = id >= 147456;
  int rem = id - set * 147456;
  int r = rem >> 14, n = (rem >> 7) & 127, k = rem & 127;
  const float* rel = set ? rel2 : rel1;
  const float* root = set ? root2 : root1;
  float v = (r < RR) ? rel[((size_t)r * DD + k) * DD + n] : root[(size_t)k * DD + n];
  wt[id] = f2bf(v);
}

// ---------------------------------------------------------------------------
// Counts: ONE atomic per edge. The atomic's return IS the edge's rank within
// its (dst,r) segment (saved to erank -> place2 needs no atomic). The (r,src)
// usage flag is a benign-race plain byte store (all racers write 1).
// ---------------------------------------------------------------------------
__global__ __launch_bounds__(256) void count_all(
    const int* __restrict__ ei, const int* __restrict__ et,
    int* __restrict__ cntdr, unsigned char* __restrict__ used,
    int* __restrict__ erank)
{
  int e = blockIdx.x * 256 + threadIdx.x;
  int src = ei[e], dst = ei[EE + e], r = et[e];
  erank[e] = atomicAdd(&cntdr[dst * RR + r], 1);
  used[r * NN + src] = 1;              // benign race: identical value
}

// ---------------------------------------------------------------------------
// 3-phase exclusive scans.
// scan_a: block sums of int array. scan_a_u8: block counts of nonzero bytes.
// ---------------------------------------------------------------------------
__global__ __launch_bounds__(256) void scan_a(
    const int4* __restrict__ c4, int n4, int* __restrict__ bsum)
{
  int t = threadIdx.x;
  int s = 0;
#pragma unroll
  for (int i = 0; i < 4; ++i) {
    int idx = blockIdx.x * 1024 + i * 256 + t;
    if (idx < n4) { int4 v = c4[idx]; s += v.x + v.y + v.z + v.w; }
  }
  __shared__ int wsum[4];
  for (int d = 32; d; d >>= 1) s += __shfl_xor(s, d, 64);
  if ((t & 63) == 0) wsum[t >> 6] = s;
  __syncthreads();
  if (t == 0) bsum[blockIdx.x] = wsum[0] + wsum[1] + wsum[2] + wsum[3];
}

__global__ __launch_bounds__(256) void scan_a_u8(
    const uint4v* __restrict__ c, int n16, int* __restrict__ bsum)
{
  int t = threadIdx.x;
  int idx = blockIdx.x * 256 + t;              // one 16-byte group / thread
  int s = 0;
  if (idx < n16) {
    uint4v v = c[idx];
#pragma unroll
    for (int w = 0; w < 4; ++w) {
      unsigned u = v[w];
      s += ((u & 0x000000FFu) ? 1 : 0) + ((u & 0x0000FF00u) ? 1 : 0)
         + ((u & 0x00FF0000u) ? 1 : 0) + ((u & 0xFF000000u) ? 1 : 0);
    }
  }
  __shared__ int wsum[4];
  for (int d = 32; d; d >>= 1) s += __shfl_xor(s, d, 64);
  if ((t & 63) == 0) wsum[t >> 6] = s;
  __syncthreads();
  if (t == 0) bsum[blockIdx.x] = wsum[0] + wsum[1] + wsum[2] + wsum[3];
}

__global__ void scan_b(const int* __restrict__ bsum, int nsb,
                       int* __restrict__ bbase, int* __restrict__ tot)
{
  int lane = threadIdx.x;                         // 64 threads
  int v[4]; int s = 0;
#pragma unroll
  for (int i = 0; i < 4; ++i) {
    int idx = lane * 4 + i;
    v[i] = (idx < nsb) ? bsum[idx] : 0; s += v[i];
  }
  int inc = s;
  for (int d = 1; d < 64; d <<= 1) {
    int o = __shfl_up(inc, d, 64);
    if (lane >= d) inc += o;
  }
  int running = inc - s;
#pragma unroll
  for (int i = 0; i < 4; ++i) {
    int idx = lane * 4 + i;
    if (idx < nsb) { bbase[idx] = running; running += v[i]; }
  }
  if (lane == 63 && tot != nullptr) tot[0] = inc;
}

// exclusive scan of int counts -> rowptr_dr [n+1] (last = EE)
__global__ __launch_bounds__(256) void scan_c(
    const int* __restrict__ cnt, const int* __restrict__ bbase, int n,
    int* __restrict__ out0)
{
  int t = threadIdx.x;
  int base = blockIdx.x * 4096 + t * 16;
  int v[16]; int s = 0;
#pragma unroll
  for (int i = 0; i < 16; ++i) {
    int idx = base + i;
    v[i] = (idx < n) ? cnt[idx] : 0;
    s += v[i];
  }
  int lane = t & 63, wid = t >> 6;
  int inc = s;
  for (int d = 1; d < 64; d <<= 1) {
    int o = __shfl_up(inc, d, 64);
    if (lane >= d) inc += o;
  }
  __shared__ int wsum[4];
  if (lane == 63) wsum[wid] = inc;
  __syncthreads();
  int wb = 0;
  for (int w = 0; w < wid; ++w) wb += wsum[w];
  int running = bbase[blockIdx.x] + wb + (inc - s);
#pragma unroll
  for (int i = 0; i < 16; ++i) {
    int idx = base + i;
    if (idx < n) { out0[idx] = running; running += v[i]; }
  }
  if (blockIdx.x == 0 && t == 0) out0[n] = EE;
}

// rank-compaction scan over byte flags: out0 = raw grank or -1; ubp[r] at r*NN.
__global__ __launch_bounds__(256) void scan_c_u8(
    const unsigned char* __restrict__ used, const int* __restrict__ bbase, int n,
    int* __restrict__ out0, int* __restrict__ ubp)
{
  int t = threadIdx.x;
  int base = blockIdx.x * 4096 + t * 16;
  int v[16]; int s = 0;
  if (base < n) {                       // 16 | n, so all-or-nothing per thread
    uint4v u = *(const uint4v*)(used + base);
    unsigned um[4]; *(uint4v*)um = u;
#pragma unroll
    for (int w = 0; w < 4; ++w)
#pragma unroll
      for (int b = 0; b < 4; ++b) {
        v[w * 4 + b] = ((um[w] >> (8 * b)) & 0xFFu) != 0;
        s += v[w * 4 + b];
      }
  } else {
#pragma unroll
    for (int i = 0; i < 16; ++i) v[i] = 0;
  }
  int lane = t & 63, wid = t >> 6;
  int inc = s;
  for (int d = 1; d < 64; d <<= 1) {
    int o = __shfl_up(inc, d, 64);
    if (lane >= d) inc += o;
  }
  __shared__ int wsum[4];
  if (lane == 63) wsum[wid] = inc;
  __syncthreads();
  int wb = 0;
  for (int w = 0; w < wid; ++w) wb += wsum[w];
  int running = bbase[blockIdx.x] + wb + (inc - s);
#pragma unroll
  for (int i = 0; i < 16; ++i) {
    int idx = base + i;
    if (idx < n) {
      if (idx % NN == 0) ubp[idx / NN] = running;
      out0[idx] = v[i] ? running : -1;
      running += v[i];
    }
  }
}

// ---------------------------------------------------------------------------
// pb[r]: 64-padded base of relation r's Y region; pb[8]=root base; pb[9]=end.
// ---------------------------------------------------------------------------
__global__ void pb_kernel(const int* __restrict__ ub, const int* __restrict__ tot,
                          int* __restrict__ pb)
{
  if (threadIdx.x == 0) {
    int base = 0;
    for (int r = 0; r < RR; ++r) {
      pb[r] = base;
      int hi = (r == RR - 1) ? tot[0] : ub[r + 1];
      int u = hi - ub[r];
      base += (u + 63) & ~63;
    }
    pb[8] = base;
    pb[9] = base + ((NN + 63) & ~63);
  }
}

// remap raw grank -> final yrow = pb[r] + (grank - ub[r]); fill ysrc.
__global__ __launch_bounds__(256) void fix_kernel(
    int* __restrict__ pidx, const int* __restrict__ ub,
    const int* __restrict__ pb, int* __restrict__ ysrc)
{
  int key = blockIdx.x * 256 + threadIdx.x;      // [0, K8)
  int g = pidx[key];
  if (g < 0) return;
  int r = key / NN, src = key - r * NN;
  int y = pb[r] + (g - ub[r]);
  pidx[key] = y;
  ysrc[y] = src;
}

// ---------------------------------------------------------------------------
// Place edges into (dst,r)-major CSR, NO atomics: slot = rowptr_dr[k]+erank[e].
// rec = (yrow of (r,src), scale = 1/segment_count).
// ---------------------------------------------------------------------------
__global__ __launch_bounds__(256) void place2(
    const int* __restrict__ ei, const int* __restrict__ et,
    const int* __restrict__ rowptr_dr, const int* __restrict__ pidx,
    const int* __restrict__ erank, int2* __restrict__ recs)
{
  int e = blockIdx.x * 256 + threadIdx.x;
  int src = ei[e], dst = ei[EE + e], r = et[e];
  int k = dst * RR + r;
  int b0 = rowptr_dr[k], b1 = rowptr_dr[k + 1];
  int slot = b0 + erank[e];
  float s = 1.0f / (float)max(b1 - b0, 1);
  int2 rec; rec.x = pidx[r * NN + src]; rec.y = __float_as_int(s);
  recs[slot] = rec;
}

// ---------------------------------------------------------------------------
// GEMM (relation-major Y): block owns 64 consecutive Y rows, one uniform W_r.
// ---------------------------------------------------------------------------
__global__ __launch_bounds__(256, 3) void gemm_y(
    const unsigned int* __restrict__ Xb,     // [NN][64] std bf16 rows
    const unsigned short* __restrict__ Wt,   // [9][128][128] bf16 [r][n][k]
    const int* __restrict__ ysrc,            // [<=640504] src per yrow (r<8)
    const int* __restrict__ pb,              // [10]
    unsigned int* __restrict__ Ypk)
{
  const int yrow0 = blockIdx.x * 64;
  if (yrow0 >= pb[9]) return;
  int r = 8;
#pragma unroll
  for (int rr = 0; rr < 8; ++rr) if (yrow0 < pb[rr + 1]) { r = rr; break; }

  __shared__ unsigned short As[64 * 128];    // 16 KB
  const int tid = threadIdx.x;
  const int wave = tid >> 6, lane = tid & 63;
  const int quad = lane >> 4, mr = lane & 15;
  const int pb8 = pb[8];

  // ---- gather A rows (rotated by (row&15)*8 shorts) ----
  {
    int row = tid >> 2, q = tid & 3;
    int yrow = yrow0 + row;
    int src;
    if (r < RR) src = ysrc[yrow];            // pad rows -> 0 (memset), harmless
    else { src = yrow - pb8; if (src >= NN) src = 0; }
    const uint4v* xs = (const uint4v*)(Xb + (size_t)src * 64 + q * 16);
#pragma unroll
    for (int c = 0; c < 4; ++c) {
      uint4v v = xs[c];
      int pos = (q * 32 + c * 8 + (row & 15) * 8) & 127;
      *(uint4v*)&As[row * 128 + pos] = v;
    }
  }
  // ---- B fragments direct from L2 (wave owns n-cols [32w, 32w+32)) ----
  const unsigned short* wr = Wt + (size_t)r * 16384 + (size_t)(wave * 32 + mr) * 128 + quad * 8;
  short8 b0[4], b1[4];
#pragma unroll
  for (int ks = 0; ks < 4; ++ks) {
    b0[ks] = *(const short8*)(wr + ks * 32);
    b1[ks] = *(const short8*)(wr + 16 * 128 + ks * 32);
  }
  __syncthreads();

  floatx4 acc[4][2];
#pragma unroll
  for (int mi = 0; mi < 4; ++mi) {
    acc[mi][0] = (floatx4){0.f, 0.f, 0.f, 0.f};
    acc[mi][1] = (floatx4){0.f, 0.f, 0.f, 0.f};
  }
#pragma unroll
  for (int ks = 0; ks < 4; ++ks) {
    short8 a[4];
#pragma unroll
    for (int mi = 0; mi < 4; ++mi)
      a[mi] = *(const short8*)&As[(mi * 16 + mr) * 128 +
                                  ((ks * 32 + quad * 8 + mr * 8) & 127)];
#pragma unroll
    for (int mi = 0; mi < 4; ++mi) {
      acc[mi][0] = __builtin_amdgcn_mfma_f32_16x16x32_bf16(a[mi], b0[ks], acc[mi][0], 0, 0, 0);
      acc[mi][1] = __builtin_amdgcn_mfma_f32_16x16x32_bf16(a[mi], b1[ks], acc[mi][1], 0, 0, 0);
    }
  }
  // ---- dense store: uint (wave*16+mr) of yrow covers cols 32w+mr, 32w+16+mr
#pragma unroll
  for (int mi = 0; mi < 4; ++mi)
#pragma unroll
    for (int rg = 0; rg < 4; ++rg)
      Ypk[(size_t)(yrow0 + mi * 16 + quad * 4 + rg) * 64 + wave * 16 + mr] =
          pk2bf(acc[mi][0][rg], acc[mi][1][rg]);
}

// ---------------------------------------------------------------------------
// Aggregation: out[v] = relu(bias + Yroot[v] + sum_e s_e * Y[yrow_e]).
// CSR is (dst,r)-major: row v spans rowptr_dr[v*8] .. rowptr_dr[(v+1)*8].
// ---------------------------------------------------------------------------
__global__ __launch_bounds__(256) void aggregate(
    const unsigned int* __restrict__ Ypk,
    const int* __restrict__ rowptr,          // rowptr_dr [K8+1]
    const int2* __restrict__ recs,           // [EE]
    const int* __restrict__ pb,
    const float* __restrict__ bias,          // [128]
    void* __restrict__ outp, int out_bf16)
{
  int gid = blockIdx.x * 256 + threadIdx.x;  // exactly NN*8 threads
  int v = gid >> 3, o = gid & 7;
  int c0 = 32 * (o >> 1) + 8 * (o & 1);      // lo-col base; hi at c0+16
  int pb8 = pb[8];

  float lo[8], hi[8];
  {
    const uint4v* rp = (const uint4v*)(Ypk + (size_t)(pb8 + v) * 64 + o * 8);
    uint4v u0 = rp[0], u1 = rp[1];
    unsigned um[8];
    *(uint4v*)&um[0] = u0; *(uint4v*)&um[4] = u1;
#pragma unroll
    for (int j = 0; j < 8; ++j) {
      lo[j] = bias[c0 + j] + bflo(um[j]);
      hi[j] = bias[c0 + 16 + j] + bfhi(um[j]);
    }
  }

  int beg = rowptr[v * RR], end = rowptr[v * RR + RR];
  if (beg < end) {
    int2 rec = recs[beg];
    const uint4v* yp = (const uint4v*)(Ypk + (size_t)rec.x * 64 + o * 8);
    uint4v c0v = yp[0], c1v = yp[1];
    for (int e = beg; e < end; ++e) {
      int2 nrec = rec;
      uint4v n0 = c0v, n1 = c1v;
      if (e + 1 < end) {
        nrec = recs[e + 1];
        const uint4v* np = (const uint4v*)(Ypk + (size_t)nrec.x * 64 + o * 8);
        n0 = np[0]; n1 = np[1];
      }
      float s = __int_as_float(rec.y);
      unsigned um[8];
      *(uint4v*)&um[0] = c0v; *(uint4v*)&um[4] = c1v;
#pragma unroll
      for (int j = 0; j < 8; ++j) {
        lo[j] = fmaf(s, bflo(um[j]), lo[j]);
        hi[j] = fmaf(s, bfhi(um[j]), hi[j]);
      }
      rec = nrec; c0v = n0; c1v = n1;
    }
  }

#pragma unroll
  for (int j = 0; j < 8; ++j) {
    lo[j] = fmaxf(lo[j], 0.f);
    hi[j] = fmaxf(hi[j], 0.f);
  }

  if (out_bf16) {
    unsigned int* h = (unsigned int*)outp;   // std rows: uint j = cols 2j|2j+1
    uint4v wl, wh;
#pragma unroll
    for (int t = 0; t < 4; ++t) {
      wl[t] = pk2bf(lo[2 * t], lo[2 * t + 1]);
      wh[t] = pk2bf(hi[2 * t], hi[2 * t + 1]);
    }
    *(uint4v*)&h[(size_t)v * 64 + c0 / 2] = wl;
    *(uint4v*)&h[(size_t)v * 64 + c0 / 2 + 8] = wh;
  } else {
    float* out = (float*)outp;
    float4* dl = (float4*)(out + (size_t)v * 128 + c0);
    float4* dh = (float4*)(out + (size_t)v * 128 + c0 + 16);
    dl[0] = make_float4(lo[0], lo[1], lo[2], lo[3]);
    dl[1] = make_float4(lo[4], lo[5], lo[6], lo[7]);
    dh[0] = make_float4(hi[0], hi[1], hi[2], hi[3]);
    dh[1] = make_float4(hi[4], hi[5], hi[6], hi[7]);
  }
}

// ---------------------------------------------------------------------------
extern "C" void kernel_launch(void* const* d_in, const int* in_sizes, int n_in,
                              void* d_out, int out_size, void* d_ws, size_t ws_size,
                              hipStream_t stream) {
  const float* x       = (const float*)d_in[0];
  const int*   ei      = (const int*)d_in[1];
  const int*   et      = (const int*)d_in[2];
  const float* rel_w1  = (const float*)d_in[3];
  const float* root_w1 = (const float*)d_in[4];
  const float* b1      = (const float*)d_in[5];
  const float* rel_w2  = (const float*)d_in[6];
  const float* root_w2 = (const float*)d_in[7];
  const float* b2      = (const float*)d_in[8];

  char* ws = (char*)d_ws;
  size_t off = 0;
  auto alloc = [&](size_t bytes) { char* p = ws + off; off = (off + bytes + 255) & ~(size_t)255; return p; };
  unsigned int*   Ypk   = (unsigned int*)alloc((size_t)(EE + NN + 1024) * 64 * 4); // 189.7 MB
  unsigned int*   Xb    = (unsigned int*)alloc((size_t)NN * 64 * 4);         // 25.6 MB
  unsigned int*   h1    = (unsigned int*)alloc((size_t)NN * 64 * 4);         // 25.6 MB
  unsigned short* Wt    = (unsigned short*)alloc((size_t)2 * 9 * DD * DD * 2);
  // ---- zero-span (one memset): cntdr, used, ysrc ----
  int*            cntdr = (int*)alloc((size_t)K8 * 4);                       // 3.2 MB
  unsigned char*  used  = (unsigned char*)alloc((size_t)K8);                 // 0.8 MB
  int*            ysrc  = (int*)alloc((size_t)(EE + 1024) * 4);              // 2.56 MB
  char*           zend  = ws + off;
  // ---- rest ----
  int*            rowptr_dr = (int*)alloc((size_t)(K8 + 1) * 4);             // 3.2 MB
  int*            erank = (int*)alloc((size_t)EE * 4);                       // 2.56 MB
  int*            pidx  = (int*)alloc((size_t)K8 * 4);                       // 3.2 MB
  int2*           recs  = (int2*)alloc((size_t)EE * 8);                      // 5.12 MB
  int*            bsumA = (int*)alloc((size_t)NSB2 * 4);
  int*            bbaseA= (int*)alloc((size_t)NSB2 * 4);
  int*            bsumB = (int*)alloc((size_t)NSB2 * 4);
  int*            bbaseB= (int*)alloc((size_t)NSB2 * 4);
  int*            ub    = (int*)alloc(64);
  int*            pb    = (int*)alloc(64);
  int*            Ptot  = (int*)alloc(64);

  hipMemsetAsync(cntdr, 0, (size_t)(zend - (char*)cntdr), stream);

  xb_prep<<<(NN * 16) / 256, 256, 0, stream>>>(x, Xb);
  w_prep_all<<<(2 * 9 * DD * DD) / 256, 256, 0, stream>>>(rel_w1, root_w1, rel_w2, root_w2, Wt);
  count_all<<<EE / 256, 256, 0, stream>>>(ei, et, cntdr, used, erank);

  // (dst,r)-major CSR rowptr: exclusive scan over cntdr [K8]
  scan_a<<<NSB2, 256, 0, stream>>>((const int4*)cntdr, K8 / 4, bsumA);
  scan_b<<<1, 64, 0, stream>>>(bsumA, NSB2, bbaseA, nullptr);
  scan_c<<<NSB2, 256, 0, stream>>>(cntdr, bbaseA, K8, rowptr_dr);

  // (r,src) usage compaction: rank-scan over byte flags -> pidx, ub
  scan_a_u8<<<NSB2, 256, 0, stream>>>((const uint4v*)used, K8 / 16, bsumB);
  scan_b<<<1, 64, 0, stream>>>(bsumB, NSB2, bbaseB, Ptot);
  scan_c_u8<<<NSB2, 256, 0, stream>>>(used, bbaseB, K8, pidx, ub);
  pb_kernel<<<1, 64, 0, stream>>>(ub, Ptot, pb);
  fix_kernel<<<K8 / 256, 256, 0, stream>>>(pidx, ub, pb, ysrc);

  place2<<<EE / 256, 256, 0, stream>>>(ei, et, rowptr_dr, pidx, erank, recs);

  const int AB = (NN * 8) / 256;   // 3125

  gemm_y<<<GBMAX, 256, 0, stream>>>(Xb, Wt, ysrc, pb, Ypk);
  aggregate<<<AB, 256, 0, stream>>>(Ypk, rowptr_dr, recs, pb, b1, h1, 1);
  gemm_y<<<GBMAX, 256, 0, stream>>>(h1, Wt + (size_t)9 * DD * DD, ysrc, pb, Ypk);
  aggregate<<<AB, 256, 0, stream>>>(Ypk, rowptr_dr, recs, pb, b2, d_out, 0);
}